// Round 6
// baseline (405.861 us; speedup 1.0000x reference)
//
#include <hip/hip_runtime.h>

#define HDIM 128

typedef unsigned int uint;
typedef unsigned short ushort;
typedef __attribute__((ext_vector_type(8))) short short8;
typedef __attribute__((ext_vector_type(4))) float f32x4;

typedef __attribute__((address_space(3))) uint  lds_u32_t;
typedef const __attribute__((address_space(1))) uint g_u32_t;
#define GLDS16(gp, lp) __builtin_amdgcn_global_load_lds((g_u32_t*)(gp), (lds_u32_t*)(lp), 16, 0, 0)

// round-to-nearest-even float -> bf16 bits
__device__ inline ushort f2bf(float f) {
    uint u = __float_as_uint(f);
    uint rounding = 0x7fffu + ((u >> 16) & 1u);
    return (ushort)((u + rounding) >> 16);
}
__device__ inline float bf2f(ushort h) { return __uint_as_float(((uint)h) << 16); }

__device__ inline float4 bf4_to_f4(uint2 u) {
    float4 r;
    r.x = __uint_as_float(u.x << 16);
    r.y = __uint_as_float(u.x & 0xffff0000u);
    r.z = __uint_as_float(u.y << 16);
    r.w = __uint_as_float(u.y & 0xffff0000u);
    return r;
}

// ======================= CSR build =======================

__global__ __launch_bounds__(256) void k_count(const int* __restrict__ dst,
                                               int* __restrict__ cnt,
                                               int* __restrict__ rank, int e) {
    int i = blockIdx.x * 256 + threadIdx.x;
    if (i < e) rank[i] = atomicAdd(&cnt[dst[i]], 1);
}

__global__ __launch_bounds__(256) void k_dinv(const int* __restrict__ cnt,
                                              float* __restrict__ dinv, int n) {
    int i = blockIdx.x * 256 + threadIdx.x;
    if (i < n) dinv[i] = rsqrtf((float)(cnt[i] + 1));   // +1 self-loop
}

__global__ __launch_bounds__(256) void k_scan1(const int* __restrict__ cnt,
                                               int* __restrict__ offs,
                                               int* __restrict__ bsum, int n) {
    __shared__ int sm[256];
    int tid = threadIdx.x;
    int i = blockIdx.x * 256 + tid;
    int v = (i < n) ? cnt[i] : 0;
    sm[tid] = v;
    __syncthreads();
    for (int off = 1; off < 256; off <<= 1) {
        int t = (tid >= off) ? sm[tid - off] : 0;
        __syncthreads();
        sm[tid] += t;
        __syncthreads();
    }
    if (i < n) offs[i] = sm[tid] - v;
    if (tid == 255) bsum[blockIdx.x] = sm[255];
}

__global__ __launch_bounds__(512) void k_scan2(int* __restrict__ bsum, int nb) {
    __shared__ int sm[512];
    int tid = threadIdx.x;
    int v = (tid < nb) ? bsum[tid] : 0;
    sm[tid] = v;
    __syncthreads();
    for (int off = 1; off < 512; off <<= 1) {
        int t = (tid >= off) ? sm[tid - off] : 0;
        __syncthreads();
        sm[tid] += t;
        __syncthreads();
    }
    if (tid < nb) bsum[tid] = sm[tid] - v;
}

__global__ __launch_bounds__(256) void k_scan3(int* __restrict__ offs,
                                               const int* __restrict__ bsum,
                                               int n, int e) {
    int i = blockIdx.x * 256 + threadIdx.x;
    if (i < n) offs[i] += bsum[blockIdx.x];
    if (i == 0) offs[n] = e;
}

__global__ __launch_bounds__(256) void k_fill(const int* __restrict__ src,
                                              const int* __restrict__ dst,
                                              const int* __restrict__ offs,
                                              const int* __restrict__ rank,
                                              int* __restrict__ csr, int e) {
    int i = blockIdx.x * 256 + threadIdx.x;
    if (i < e) {
        csr[offs[dst[i]] + rank[i]] = src[i];
    }
}

// =============== W prep: split-transpose W[K][128] -> wt_hi/wt_lo [128][K] bf16 ===============

__global__ __launch_bounds__(256) void k_prep_w(const float* __restrict__ W,
                                                ushort* __restrict__ wt_hi,
                                                ushort* __restrict__ wt_lo, int K) {
    int idx = blockIdx.x * 256 + threadIdx.x;
    if (idx < K * HDIM) {
        int k = idx >> 7;       // row in W
        int c = idx & 127;      // col in W
        float v = W[idx];
        ushort h = f2bf(v);
        ushort l = f2bf(v - bf2f(h));
        wt_hi[(size_t)c * K + k] = h;
        wt_lo[(size_t)c * K + k] = l;
    }
}

// =============== MFMA GEMM: g = bf16( dinv .* (X @ W) ), split-bf16 ===============
// A = W^T (wh/wl planes), B = X (XF32: fp32 input, split in-kernel;
// else: bf16 hi/lo planes staged via global_load_lds).
// LDS: 4 linear tiles [128][32] bf16 (8KB each, 32KB total); 2-barrier K-loop.
// 4 waves, 2x2 grid of 64x64; 16x16x32 MFMA, 3 terms (hh, hl, lh).

template<int K, bool XF32>
__global__ __launch_bounds__(256) void k_mm(const float* __restrict__ Xf,
                                            const ushort* __restrict__ XH,
                                            const ushort* __restrict__ XL,
                                            const ushort* __restrict__ WH,
                                            const ushort* __restrict__ WL,
                                            const float* __restrict__ dinv,
                                            ushort* __restrict__ g, int n)
{
    __shared__ ushort lds[4 * 4096];   // tiles: xh@0, xl@4096, wh@8192, wl@12288

    const int tid  = threadIdx.x;
    const int wv   = tid >> 6;
    const int lane = tid & 63;
    const int r    = lane & 15;
    const int gq8  = (lane >> 4) * 8;
    const int row0 = blockIdx.x * 128;

    ushort* const Lxh = lds;
    ushort* const Lxl = lds + 4096;
    ushort* const Lwh = lds + 8192;
    ushort* const Lwl = lds + 12288;

    // glds staging assignment: wave wv stages tile wv (XF32: only waves 2,3 -> W tiles)
    const ushort* plane = (wv == 0) ? XH : (wv == 1) ? XL : (wv == 2) ? WH : WL;
    const size_t  rbase = (wv < 2) ? (size_t)row0 : 0;
    ushort* const ldst  = lds + wv * 4096;
    const int rsub = lane >> 2;          // 16 rows per 1KB chunk, 4 lanes/row
    const int csub = (lane & 3) * 8;     // 16B sub-chunk (8 ushorts)

    f32x4 acc[4][4];
    #pragma unroll
    for (int m = 0; m < 4; m++)
        #pragma unroll
        for (int nf = 0; nf < 4; nf++)
            acc[m][nf] = (f32x4){0.f, 0.f, 0.f, 0.f};

    const int xbase = (wv >> 1) * 64;
    const int wbase = (wv & 1) * 64;

    const int srow  = tid >> 1;          // XF32 staging: row, k-half
    const int shalf = tid & 1;

    for (int k0 = 0; k0 < K; k0 += 32) {
        if constexpr (XF32) {
            // W tiles via global_load_lds (waves 2,3)
            if (wv >= 2) {
                #pragma unroll
                for (int i = 0; i < 8; i++) {
                    const ushort* gp = plane + (rbase + i * 16 + rsub) * (size_t)K + k0 + csub;
                    GLDS16(gp, ldst + i * 512);
                }
            }
            // X tile: fp32 load -> split bf16 -> LDS (all threads)
            float4 f0, f1, f2, f3;
            int grow = row0 + srow;
            if (grow < n) {
                const float4* p = (const float4*)(Xf + (size_t)grow * K + k0 + shalf * 16);
                f0 = p[0]; f1 = p[1]; f2 = p[2]; f3 = p[3];
            } else {
                f0 = f1 = f2 = f3 = make_float4(0.f, 0.f, 0.f, 0.f);
            }
            float v[16] = {f0.x, f0.y, f0.z, f0.w, f1.x, f1.y, f1.z, f1.w,
                           f2.x, f2.y, f2.z, f2.w, f3.x, f3.y, f3.z, f3.w};
            uint h[8], l[8];
            #pragma unroll
            for (int q = 0; q < 8; q++) {
                ushort h0 = f2bf(v[2 * q]), h1 = f2bf(v[2 * q + 1]);
                h[q] = (uint)h0 | ((uint)h1 << 16);
                ushort l0 = f2bf(v[2 * q] - bf2f(h0));
                ushort l1 = f2bf(v[2 * q + 1] - bf2f(h1));
                l[q] = (uint)l0 | ((uint)l1 << 16);
            }
            int sb = srow * 32 + shalf * 16;
            *(uint4*)&Lxh[sb]     = make_uint4(h[0], h[1], h[2], h[3]);
            *(uint4*)&Lxh[sb + 8] = make_uint4(h[4], h[5], h[6], h[7]);
            *(uint4*)&Lxl[sb]     = make_uint4(l[0], l[1], l[2], l[3]);
            *(uint4*)&Lxl[sb + 8] = make_uint4(l[4], l[5], l[6], l[7]);
        } else {
            // all 4 tiles via global_load_lds, one tile per wave
            #pragma unroll
            for (int i = 0; i < 8; i++) {
                const ushort* gp = plane + (rbase + i * 16 + rsub) * (size_t)K + k0 + csub;
                GLDS16(gp, ldst + i * 512);
            }
        }
        __syncthreads();   // drains vmcnt (glds) + lds writes

        short8 bh[4], bl[4];
        #pragma unroll
        for (int nf = 0; nf < 4; nf++) {
            bh[nf] = *(const short8*)&Lxh[(xbase + nf * 16 + r) * 32 + gq8];
            bl[nf] = *(const short8*)&Lxl[(xbase + nf * 16 + r) * 32 + gq8];
        }
        #pragma unroll
        for (int m = 0; m < 4; m++) {
            short8 ah = *(const short8*)&Lwh[(wbase + m * 16 + r) * 32 + gq8];
            short8 al = *(const short8*)&Lwl[(wbase + m * 16 + r) * 32 + gq8];
            #pragma unroll
            for (int nf = 0; nf < 4; nf++) {
                acc[m][nf] = __builtin_amdgcn_mfma_f32_16x16x32_bf16(ah, bh[nf], acc[m][nf], 0, 0, 0);
                acc[m][nf] = __builtin_amdgcn_mfma_f32_16x16x32_bf16(ah, bl[nf], acc[m][nf], 0, 0, 0);
                acc[m][nf] = __builtin_amdgcn_mfma_f32_16x16x32_bf16(al, bh[nf], acc[m][nf], 0, 0, 0);
            }
        }
        __syncthreads();   // protect LDS from next iter's staging
    }

    // epilogue: D[wcol][xrow]; scale by dinv[xrow], store bf16
    #pragma unroll
    for (int nf = 0; nf < 4; nf++) {
        int xrow = row0 + xbase + nf * 16 + r;
        if (xrow < n) {
            float di = dinv[xrow];
            #pragma unroll
            for (int m = 0; m < 4; m++) {
                int wcol = wbase + m * 16 + gq8 / 2;   // gq*4
                f32x4 a = acc[m][nf];
                uint2 pk;
                pk.x = (uint)f2bf(a[0] * di) | ((uint)f2bf(a[1] * di) << 16);
                pk.y = (uint)f2bf(a[2] * di) | ((uint)f2bf(a[3] * di) << 16);
                *(uint2*)(g + (size_t)xrow * HDIM + wcol) = pk;
            }
        }
    }
}

// ===== gather + finish: o = [relu](dinv*(g[d] + sum g[src]) + b) =====
// EMIT_SPLIT: write bf16 hi/lo activation planes (next layer's GEMM input);
// else: write fp32 out (final layer).

template<bool RELU, bool EMIT_SPLIT>
__global__ __launch_bounds__(256) void k_gather(const ushort* __restrict__ g,
                                                const int* __restrict__ csr,
                                                const int* __restrict__ offs,
                                                const float* __restrict__ dinv,
                                                const float* __restrict__ bias,
                                                float* __restrict__ out,
                                                ushort* __restrict__ ah,
                                                ushort* __restrict__ al, int n)
{
    int t    = blockIdx.x * 256 + threadIdx.x;
    int node = t >> 5;
    int l    = t & 31;
    if (node >= n) return;

    int e0 = offs[node];
    int e1 = offs[node + 1];

    float4 acc = bf4_to_f4(*(const uint2*)(g + (size_t)node * HDIM + l * 4));

    int e = e0;
    for (; e + 4 <= e1; e += 4) {
        int s0 = csr[e], s1 = csr[e + 1], s2 = csr[e + 2], s3 = csr[e + 3];
        float4 v0 = bf4_to_f4(*(const uint2*)(g + (size_t)s0 * HDIM + l * 4));
        float4 v1 = bf4_to_f4(*(const uint2*)(g + (size_t)s1 * HDIM + l * 4));
        float4 v2 = bf4_to_f4(*(const uint2*)(g + (size_t)s2 * HDIM + l * 4));
        float4 v3 = bf4_to_f4(*(const uint2*)(g + (size_t)s3 * HDIM + l * 4));
        acc.x += v0.x + v1.x + v2.x + v3.x;
        acc.y += v0.y + v1.y + v2.y + v3.y;
        acc.z += v0.z + v1.z + v2.z + v3.z;
        acc.w += v0.w + v1.w + v2.w + v3.w;
    }
    for (; e < e1; e++) {
        int s = csr[e];
        float4 v = bf4_to_f4(*(const uint2*)(g + (size_t)s * HDIM + l * 4));
        acc.x += v.x; acc.y += v.y; acc.z += v.z; acc.w += v.w;
    }

    float di  = dinv[node];
    float4 bb = *(const float4*)(bias + l * 4);
    float4 o;
    o.x = fmaf(di, acc.x, bb.x);
    o.y = fmaf(di, acc.y, bb.y);
    o.z = fmaf(di, acc.z, bb.z);
    o.w = fmaf(di, acc.w, bb.w);
    if (RELU) {
        o.x = fmaxf(o.x, 0.f); o.y = fmaxf(o.y, 0.f);
        o.z = fmaxf(o.z, 0.f); o.w = fmaxf(o.w, 0.f);
    }
    if (EMIT_SPLIT) {
        ushort h0 = f2bf(o.x), h1 = f2bf(o.y), h2 = f2bf(o.z), h3 = f2bf(o.w);
        uint2 ph, pl;
        ph.x = (uint)h0 | ((uint)h1 << 16);
        ph.y = (uint)h2 | ((uint)h3 << 16);
        pl.x = (uint)f2bf(o.x - bf2f(h0)) | ((uint)f2bf(o.y - bf2f(h1)) << 16);
        pl.y = (uint)f2bf(o.z - bf2f(h2)) | ((uint)f2bf(o.w - bf2f(h3)) << 16);
        *(uint2*)(ah + (size_t)node * HDIM + l * 4) = ph;
        *(uint2*)(al + (size_t)node * HDIM + l * 4) = pl;
    } else {
        *(float4*)(out + (size_t)node * HDIM + l * 4) = o;
    }
}

// ======================= launch =======================

extern "C" void kernel_launch(void* const* d_in, const int* in_sizes, int n_in,
                              void* d_out, int out_size, void* d_ws, size_t ws_size,
                              hipStream_t stream)
{
    const float* x  = (const float*)d_in[0];
    const int*   ei = (const int*)d_in[1];
    const float* W1 = (const float*)d_in[2];
    const float* b1 = (const float*)d_in[3];
    const float* W2 = (const float*)d_in[4];
    const float* b2 = (const float*)d_in[5];
    const float* W3 = (const float*)d_in[6];
    const float* b3 = (const float*)d_in[7];
    float* out = (float*)d_out;

    const int n = in_sizes[0] / 256;   // IN = 256
    const int E = in_sizes[1] / 2;
    const int* src = ei;
    const int* dst = ei + E;

    // workspace layout (bytes):
    //   dinv @0, cnt @512K, offs @1M, bsum @1.5M, csr @1600K (6.4MB),
    //   rank @8M (6.4MB), wh @14.5M (128K slot), wl @14.75M,
    //   g @16M (25.7MB), xh2 @42M (25.7MB), xl2 @68M (25.7MB)  => ~94MB
    char*   ws   = (char*)d_ws;
    float*  dinv = (float*)(ws);
    int*    cnt  = (int*)(ws + (512 << 10));
    int*    offs = (int*)(ws + (1 << 20));
    int*    bsum = (int*)(ws + 1536 * 1024);
    int*    csr  = (int*)(ws + 1600 * 1024);
    int*    rank = (int*)(ws + (size_t)(8 << 20));
    ushort* wh   = (ushort*)(ws + 14848 * 1024);
    ushort* wl   = (ushort*)(ws + 15104 * 1024);
    ushort* g    = (ushort*)(ws + (size_t)(16 << 20));
    ushort* xh2  = (ushort*)(ws + (size_t)(42 << 20));
    ushort* xl2  = (ushort*)(ws + (size_t)(68 << 20));

    dim3 blk(256);
    int ngrid = (n + 255) / 256;
    int egrid = (E + 255) / 256;

    // ---- CSR build + norms ----
    hipMemsetAsync(cnt, 0, (size_t)n * 4, stream);
    k_count<<<egrid, blk, 0, stream>>>(dst, cnt, rank, E);
    k_dinv<<<ngrid, blk, 0, stream>>>(cnt, dinv, n);
    k_scan1<<<ngrid, blk, 0, stream>>>(cnt, offs, bsum, n);
    k_scan2<<<1, 512, 0, stream>>>(bsum, ngrid);
    k_scan3<<<ngrid, blk, 0, stream>>>(offs, bsum, n, E);
    k_fill<<<egrid, blk, 0, stream>>>(src, dst, offs, rank, csr, E);

    int mm_grid  = (n + 127) / 128;
    int gat_grid = (int)(((size_t)n * 32 + 255) / 256);

    // layer 1 (K=256, fp32 X split in-kernel)
    k_prep_w<<<(256 * HDIM + 255) / 256, blk, 0, stream>>>(W1, wh, wl, 256);
    k_mm<256, true><<<mm_grid, blk, 0, stream>>>(x, nullptr, nullptr, wh, wl, dinv, g, n);
    k_gather<true, true><<<gat_grid, blk, 0, stream>>>(g, csr, offs, dinv, b1, nullptr, xh2, xl2, n);
    // layer 2 (K=128, bf16 planes via global_load_lds)
    k_prep_w<<<(128 * HDIM + 255) / 256, blk, 0, stream>>>(W2, wh, wl, 128);
    k_mm<128, false><<<mm_grid, blk, 0, stream>>>(nullptr, xh2, xl2, wh, wl, dinv, g, n);
    k_gather<true, true><<<gat_grid, blk, 0, stream>>>(g, csr, offs, dinv, b2, nullptr, xh2, xl2, n);
    // layer 3 (K=128)
    k_prep_w<<<(128 * HDIM + 255) / 256, blk, 0, stream>>>(W3, wh, wl, 128);
    k_mm<128, false><<<mm_grid, blk, 0, stream>>>(nullptr, xh2, xl2, wh, wl, dinv, g, n);
    k_gather<false, false><<<gat_grid, blk, 0, stream>>>(g, csr, offs, dinv, b3, out, nullptr, nullptr, n);
}

// Round 7
// 404.237 us; speedup vs baseline: 1.0040x; 1.0040x over previous
//
#include <hip/hip_runtime.h>

#define HDIM 128

typedef unsigned int uint;
typedef unsigned short ushort;
typedef __attribute__((ext_vector_type(8))) short short8;
typedef __attribute__((ext_vector_type(4))) float f32x4;

typedef __attribute__((address_space(3))) uint  lds_u32_t;
typedef const __attribute__((address_space(1))) uint g_u32_t;
#define GLDS16(gp, lp) __builtin_amdgcn_global_load_lds((g_u32_t*)(gp), (lds_u32_t*)(lp), 16, 0, 0)

// round-to-nearest-even float -> bf16 bits
__device__ inline ushort f2bf(float f) {
    uint u = __float_as_uint(f);
    uint rounding = 0x7fffu + ((u >> 16) & 1u);
    return (ushort)((u + rounding) >> 16);
}
__device__ inline float bf2f(ushort h) { return __uint_as_float(((uint)h) << 16); }

__device__ inline float4 bf4_to_f4(uint2 u) {
    float4 r;
    r.x = __uint_as_float(u.x << 16);
    r.y = __uint_as_float(u.x & 0xffff0000u);
    r.z = __uint_as_float(u.y << 16);
    r.w = __uint_as_float(u.y & 0xffff0000u);
    return r;
}

// ======================= CSR build =======================

__global__ __launch_bounds__(256) void k_count(const int* __restrict__ dst,
                                               int* __restrict__ cnt,
                                               int* __restrict__ rank, int e) {
    int i = blockIdx.x * 256 + threadIdx.x;
    if (i < e) rank[i] = atomicAdd(&cnt[dst[i]], 1);
}

__global__ __launch_bounds__(256) void k_dinv(const int* __restrict__ cnt,
                                              float* __restrict__ dinv, int n) {
    int i = blockIdx.x * 256 + threadIdx.x;
    if (i < n) dinv[i] = rsqrtf((float)(cnt[i] + 1));   // +1 self-loop
}

__global__ __launch_bounds__(256) void k_scan1(const int* __restrict__ cnt,
                                               int* __restrict__ offs,
                                               int* __restrict__ bsum, int n) {
    __shared__ int sm[256];
    int tid = threadIdx.x;
    int i = blockIdx.x * 256 + tid;
    int v = (i < n) ? cnt[i] : 0;
    sm[tid] = v;
    __syncthreads();
    for (int off = 1; off < 256; off <<= 1) {
        int t = (tid >= off) ? sm[tid - off] : 0;
        __syncthreads();
        sm[tid] += t;
        __syncthreads();
    }
    if (i < n) offs[i] = sm[tid] - v;
    if (tid == 255) bsum[blockIdx.x] = sm[255];
}

__global__ __launch_bounds__(512) void k_scan2(int* __restrict__ bsum, int nb) {
    __shared__ int sm[512];
    int tid = threadIdx.x;
    int v = (tid < nb) ? bsum[tid] : 0;
    sm[tid] = v;
    __syncthreads();
    for (int off = 1; off < 512; off <<= 1) {
        int t = (tid >= off) ? sm[tid - off] : 0;
        __syncthreads();
        sm[tid] += t;
        __syncthreads();
    }
    if (tid < nb) bsum[tid] = sm[tid] - v;
}

__global__ __launch_bounds__(256) void k_scan3(int* __restrict__ offs,
                                               const int* __restrict__ bsum,
                                               int n, int e) {
    int i = blockIdx.x * 256 + threadIdx.x;
    if (i < n) offs[i] += bsum[blockIdx.x];
    if (i == 0) offs[n] = e;
}

__global__ __launch_bounds__(256) void k_fill(const int* __restrict__ src,
                                              const int* __restrict__ dst,
                                              const int* __restrict__ offs,
                                              const int* __restrict__ rank,
                                              int* __restrict__ csr, int e) {
    int i = blockIdx.x * 256 + threadIdx.x;
    if (i < e) {
        csr[offs[dst[i]] + rank[i]] = src[i];
    }
}

// ===== W prep: split-transpose W[K][128] -> tile-major swizzled planes [K/32][128][32] =====
// global 16B-unit u of row c stored at physical unit u ^ (c&3).

__global__ __launch_bounds__(256) void k_prep_w(const float* __restrict__ W,
                                                ushort* __restrict__ wt_hi,
                                                ushort* __restrict__ wt_lo, int K) {
    int idx = blockIdx.x * 256 + threadIdx.x;
    if (idx < K * HDIM) {
        int k = idx >> 7;       // row in W (k index)
        int c = idx & 127;      // col in W
        float v = W[idx];
        ushort h = f2bf(v);
        ushort l = f2bf(v - bf2f(h));
        int kt = k >> 5, kk = k & 31;
        int pos = kt * 4096 + c * 32 + (kk ^ ((c & 3) << 3));
        wt_hi[pos] = h;
        wt_lo[pos] = l;
    }
}

// =============== MFMA GEMM: g = bf16( dinv .* (X @ W) ), split-bf16 ===============
// A = W^T planes, B = X. Planes tile-major [K/32][rows][32], XOR-swizzled.
// Double-buffered LDS (64KB), T3 2-phase: STAGE(next) issued before COMPUTE(cur),
// one barrier per K-step (two for XF32 reg-staged X path).
// 4 waves, 2x2 grid of 64x64; 16x16x32 MFMA, 3 terms (hh, hl, lh).

template<int K, bool XF32>
__global__ __launch_bounds__(256) void k_mm(const float* __restrict__ Xf,
                                            const ushort* __restrict__ XH,
                                            const ushort* __restrict__ XL,
                                            const ushort* __restrict__ WH,
                                            const ushort* __restrict__ WL,
                                            const float* __restrict__ dinv,
                                            ushort* __restrict__ g, int n)
{
    constexpr int NT = K / 32;
    __shared__ ushort lds[2][4][4096];   // [buf][xh,xl,wh,wl][8KB tile]

    const int tid  = threadIdx.x;
    const int wv   = tid >> 6;
    const int lane = tid & 63;
    const int r    = lane & 15;
    const int gq8  = (lane >> 4) * 8;
    const int row0 = blockIdx.x * 128;

    // staging plane for this wave (one 8KB tile per wave)
    const ushort* plane;
    size_t ktstride;
    if (XF32) {
        plane    = (wv == 2) ? WH : WL;   // waves 0,1 unused for glds
        ktstride = 4096;
    } else {
        plane    = (wv == 0) ? XH : (wv == 1) ? XL : (wv == 2) ? WH : WL;
        ktstride = (wv < 2) ? (size_t)n * 32 : 4096;
    }
    const size_t pbase = (!XF32 && wv < 2) ? (size_t)row0 * 32 : 0;

    const int srow  = tid >> 1;          // XF32 x staging: row 0..127
    const int shalf = tid & 1;           // k-half (16 floats)
    const int swz   = srow & 3;

    f32x4 acc[4][4];
    #pragma unroll
    for (int m = 0; m < 4; m++)
        #pragma unroll
        for (int nf = 0; nf < 4; nf++)
            acc[m][nf] = (f32x4){0.f, 0.f, 0.f, 0.f};

    const int xbase = (wv >> 1) * 64;
    const int wbase = (wv & 1) * 64;

    // --- helpers ---
    auto STAGE = [&](int buf, int kt) {    // glds this wave's tile
        const ushort* src = plane + (size_t)kt * ktstride + pbase + (size_t)lane * 8;
        ushort* dst = &lds[buf][wv][0];
        #pragma unroll
        for (int i = 0; i < 8; i++)
            GLDS16(src + i * 512, dst + i * 512);
    };

    float4 xr[4];                          // XF32 prefetched x regs
    auto XLOAD = [&](int kt) {
        int grow = row0 + srow;
        if (grow < n) {
            const float4* p = (const float4*)(Xf + (size_t)grow * K + kt * 32 + shalf * 16);
            xr[0] = p[0]; xr[1] = p[1]; xr[2] = p[2]; xr[3] = p[3];
        } else {
            xr[0] = xr[1] = xr[2] = xr[3] = make_float4(0.f, 0.f, 0.f, 0.f);
        }
    };
    auto XWRITE = [&](int buf) {           // split + swizzled ds_write
        float v[16] = {xr[0].x, xr[0].y, xr[0].z, xr[0].w, xr[1].x, xr[1].y, xr[1].z, xr[1].w,
                       xr[2].x, xr[2].y, xr[2].z, xr[2].w, xr[3].x, xr[3].y, xr[3].z, xr[3].w};
        uint h[8], l[8];
        #pragma unroll
        for (int q = 0; q < 8; q++) {
            ushort h0 = f2bf(v[2 * q]), h1 = f2bf(v[2 * q + 1]);
            h[q] = (uint)h0 | ((uint)h1 << 16);
            ushort l0 = f2bf(v[2 * q] - bf2f(h0));
            ushort l1 = f2bf(v[2 * q + 1] - bf2f(h1));
            l[q] = (uint)l0 | ((uint)l1 << 16);
        }
        int uA = (2 * shalf) ^ swz;
        int uB = (2 * shalf + 1) ^ swz;
        ushort* Lxh = &lds[buf][0][0];
        ushort* Lxl = &lds[buf][1][0];
        *(uint4*)&Lxh[srow * 32 + uA * 8] = make_uint4(h[0], h[1], h[2], h[3]);
        *(uint4*)&Lxh[srow * 32 + uB * 8] = make_uint4(h[4], h[5], h[6], h[7]);
        *(uint4*)&Lxl[srow * 32 + uA * 8] = make_uint4(l[0], l[1], l[2], l[3]);
        *(uint4*)&Lxl[srow * 32 + uB * 8] = make_uint4(l[4], l[5], l[6], l[7]);
    };
    auto COMPUTE = [&](int buf) {
        const ushort* Lxh = &lds[buf][0][0];
        const ushort* Lxl = &lds[buf][1][0];
        const ushort* Lwh = &lds[buf][2][0];
        const ushort* Lwl = &lds[buf][3][0];
        const int sx = (r & 3) << 3;       // swizzle XOR (in ushorts)
        short8 bh[4], bl[4];
        #pragma unroll
        for (int nf = 0; nf < 4; nf++) {
            int off = (xbase + nf * 16 + r) * 32 + (gq8 ^ sx);
            bh[nf] = *(const short8*)&Lxh[off];
            bl[nf] = *(const short8*)&Lxl[off];
        }
        #pragma unroll
        for (int m = 0; m < 4; m++) {
            int off = (wbase + m * 16 + r) * 32 + (gq8 ^ sx);
            short8 ah = *(const short8*)&Lwh[off];
            short8 al = *(const short8*)&Lwl[off];
            #pragma unroll
            for (int nf = 0; nf < 4; nf++) {
                acc[m][nf] = __builtin_amdgcn_mfma_f32_16x16x32_bf16(ah, bh[nf], acc[m][nf], 0, 0, 0);
                acc[m][nf] = __builtin_amdgcn_mfma_f32_16x16x32_bf16(ah, bl[nf], acc[m][nf], 0, 0, 0);
                acc[m][nf] = __builtin_amdgcn_mfma_f32_16x16x32_bf16(al, bh[nf], acc[m][nf], 0, 0, 0);
            }
        }
    };

    // --- prologue ---
    int buf = 0;
    if (XF32) {
        if (wv >= 2) STAGE(0, 0);
        XLOAD(0);
        XWRITE(0);
        __syncthreads();
        for (int kt = 0; kt < NT; ++kt) {
            if (kt + 1 < NT) {
                XLOAD(kt + 1);
                if (wv >= 2) STAGE(buf ^ 1, kt + 1);
            }
            COMPUTE(buf);
            __syncthreads();               // drains W glds + lds
            if (kt + 1 < NT) XWRITE(buf ^ 1);
            __syncthreads();               // X writes visible
            buf ^= 1;
        }
    } else {
        STAGE(0, 0);
        __syncthreads();
        for (int kt = 0; kt < NT; ++kt) {
            if (kt + 1 < NT) STAGE(buf ^ 1, kt + 1);
            COMPUTE(buf);
            __syncthreads();               // drains next-stage glds; buf^1 ready
            buf ^= 1;
        }
    }

    // --- epilogue: D[wcol][xrow]; scale by dinv[xrow], store bf16 g[n][128] ---
    #pragma unroll
    for (int nf = 0; nf < 4; nf++) {
        int xrow = row0 + xbase + nf * 16 + r;
        if (xrow < n) {
            float di = dinv[xrow];
            #pragma unroll
            for (int m = 0; m < 4; m++) {
                int wcol = wbase + m * 16 + gq8 / 2;   // gq*4
                f32x4 a = acc[m][nf];
                uint2 pk;
                pk.x = (uint)f2bf(a[0] * di) | ((uint)f2bf(a[1] * di) << 16);
                pk.y = (uint)f2bf(a[2] * di) | ((uint)f2bf(a[3] * di) << 16);
                *(uint2*)(g + (size_t)xrow * HDIM + wcol) = pk;
            }
        }
    }
}

// ===== gather + finish: o = [relu](dinv*(g[d] + sum g[src]) + b) =====
// EMIT_SPLIT: write bf16 hi/lo activation planes, tile-major [4][n][32], swizzled.

template<bool RELU, bool EMIT_SPLIT>
__global__ __launch_bounds__(256) void k_gather(const ushort* __restrict__ g,
                                                const int* __restrict__ csr,
                                                const int* __restrict__ offs,
                                                const float* __restrict__ dinv,
                                                const float* __restrict__ bias,
                                                float* __restrict__ out,
                                                ushort* __restrict__ ah,
                                                ushort* __restrict__ al, int n)
{
    int t    = blockIdx.x * 256 + threadIdx.x;
    int node = t >> 5;
    int l    = t & 31;
    if (node >= n) return;

    int e0 = offs[node];
    int e1 = offs[node + 1];

    float4 acc = bf4_to_f4(*(const uint2*)(g + (size_t)node * HDIM + l * 4));

    int e = e0;
    for (; e + 4 <= e1; e += 4) {
        int s0 = csr[e], s1 = csr[e + 1], s2 = csr[e + 2], s3 = csr[e + 3];
        float4 v0 = bf4_to_f4(*(const uint2*)(g + (size_t)s0 * HDIM + l * 4));
        float4 v1 = bf4_to_f4(*(const uint2*)(g + (size_t)s1 * HDIM + l * 4));
        float4 v2 = bf4_to_f4(*(const uint2*)(g + (size_t)s2 * HDIM + l * 4));
        float4 v3 = bf4_to_f4(*(const uint2*)(g + (size_t)s3 * HDIM + l * 4));
        acc.x += v0.x + v1.x + v2.x + v3.x;
        acc.y += v0.y + v1.y + v2.y + v3.y;
        acc.z += v0.z + v1.z + v2.z + v3.z;
        acc.w += v0.w + v1.w + v2.w + v3.w;
    }
    for (; e < e1; e++) {
        int s = csr[e];
        float4 v = bf4_to_f4(*(const uint2*)(g + (size_t)s * HDIM + l * 4));
        acc.x += v.x; acc.y += v.y; acc.z += v.z; acc.w += v.w;
    }

    float di  = dinv[node];
    float4 bb = *(const float4*)(bias + l * 4);
    float4 o;
    o.x = fmaf(di, acc.x, bb.x);
    o.y = fmaf(di, acc.y, bb.y);
    o.z = fmaf(di, acc.z, bb.z);
    o.w = fmaf(di, acc.w, bb.w);
    if (RELU) {
        o.x = fmaxf(o.x, 0.f); o.y = fmaxf(o.y, 0.f);
        o.z = fmaxf(o.z, 0.f); o.w = fmaxf(o.w, 0.f);
    }
    if (EMIT_SPLIT) {
        ushort h0 = f2bf(o.x), h1 = f2bf(o.y), h2 = f2bf(o.z), h3 = f2bf(o.w);
        uint2 ph, pl;
        ph.x = (uint)h0 | ((uint)h1 << 16);
        ph.y = (uint)h2 | ((uint)h3 << 16);
        pl.x = (uint)f2bf(o.x - bf2f(h0)) | ((uint)f2bf(o.y - bf2f(h1)) << 16);
        pl.y = (uint)f2bf(o.z - bf2f(h2)) | ((uint)f2bf(o.w - bf2f(h3)) << 16);
        // tile-major [kt][n][32], swizzled: 8B-slot (l&7) at unit XOR (node&3)
        int kt = l >> 3;
        size_t base = (size_t)kt * n * 32 + (size_t)node * 32
                    + (((l & 7) * 4) ^ ((node & 3) << 3));
        *(uint2*)(ah + base) = ph;
        *(uint2*)(al + base) = pl;
    } else {
        *(float4*)(out + (size_t)node * HDIM + l * 4) = o;
    }
}

// ======================= launch =======================

extern "C" void kernel_launch(void* const* d_in, const int* in_sizes, int n_in,
                              void* d_out, int out_size, void* d_ws, size_t ws_size,
                              hipStream_t stream)
{
    const float* x  = (const float*)d_in[0];
    const int*   ei = (const int*)d_in[1];
    const float* W1 = (const float*)d_in[2];
    const float* b1 = (const float*)d_in[3];
    const float* W2 = (const float*)d_in[4];
    const float* b2 = (const float*)d_in[5];
    const float* W3 = (const float*)d_in[6];
    const float* b3 = (const float*)d_in[7];
    float* out = (float*)d_out;

    const int n = in_sizes[0] / 256;   // IN = 256
    const int E = in_sizes[1] / 2;
    const int* src = ei;
    const int* dst = ei + E;

    // workspace layout (bytes):
    //   dinv @0, cnt @512K, offs @1M, bsum @1.5M, csr @1600K (6.4MB),
    //   rank @8M (6.4MB), wh @14.5M (64KB slot), wl @14.75M,
    //   g @16M (25.7MB), xh2 @42M (25.7MB), xl2 @68M (25.7MB)
    char*   ws   = (char*)d_ws;
    float*  dinv = (float*)(ws);
    int*    cnt  = (int*)(ws + (512 << 10));
    int*    offs = (int*)(ws + (1 << 20));
    int*    bsum = (int*)(ws + 1536 * 1024);
    int*    csr  = (int*)(ws + 1600 * 1024);
    int*    rank = (int*)(ws + (size_t)(8 << 20));
    ushort* wh   = (ushort*)(ws + 14848 * 1024);
    ushort* wl   = (ushort*)(ws + 15104 * 1024);
    ushort* g    = (ushort*)(ws + (size_t)(16 << 20));
    ushort* xh2  = (ushort*)(ws + (size_t)(42 << 20));
    ushort* xl2  = (ushort*)(ws + (size_t)(68 << 20));

    dim3 blk(256);
    int ngrid = (n + 255) / 256;
    int egrid = (E + 255) / 256;

    // ---- CSR build + norms ----
    hipMemsetAsync(cnt, 0, (size_t)n * 4, stream);
    k_count<<<egrid, blk, 0, stream>>>(dst, cnt, rank, E);
    k_dinv<<<ngrid, blk, 0, stream>>>(cnt, dinv, n);
    k_scan1<<<ngrid, blk, 0, stream>>>(cnt, offs, bsum, n);
    k_scan2<<<1, 512, 0, stream>>>(bsum, ngrid);
    k_scan3<<<ngrid, blk, 0, stream>>>(offs, bsum, n, E);
    k_fill<<<egrid, blk, 0, stream>>>(src, dst, offs, rank, csr, E);

    int mm_grid  = (n + 127) / 128;
    int gat_grid = (int)(((size_t)n * 32 + 255) / 256);

    // layer 1 (K=256, fp32 X split in-kernel)
    k_prep_w<<<(256 * HDIM + 255) / 256, blk, 0, stream>>>(W1, wh, wl, 256);
    k_mm<256, true><<<mm_grid, blk, 0, stream>>>(x, nullptr, nullptr, wh, wl, dinv, g, n);
    k_gather<true, true><<<gat_grid, blk, 0, stream>>>(g, csr, offs, dinv, b1, nullptr, xh2, xl2, n);
    // layer 2 (K=128, tile-major bf16 planes via glds)
    k_prep_w<<<(128 * HDIM + 255) / 256, blk, 0, stream>>>(W2, wh, wl, 128);
    k_mm<128, false><<<mm_grid, blk, 0, stream>>>(nullptr, xh2, xl2, wh, wl, dinv, g, n);
    k_gather<true, true><<<gat_grid, blk, 0, stream>>>(g, csr, offs, dinv, b2, nullptr, xh2, xl2, n);
    // layer 3 (K=128)
    k_prep_w<<<(128 * HDIM + 255) / 256, blk, 0, stream>>>(W3, wh, wl, 128);
    k_mm<128, false><<<mm_grid, blk, 0, stream>>>(nullptr, xh2, xl2, wh, wl, dinv, g, n);
    k_gather<false, false><<<gat_grid, blk, 0, stream>>>(g, csr, offs, dinv, b3, out, nullptr, nullptr, n);
}